// Round 14
// baseline (743.914 us; speedup 1.0000x reference)
//
#include <hip/hip_runtime.h>
#include <math.h>

#define N_NEU    2048
#define BB       64
#define TT       100
#define KIN      784
#define NIN_NEU  1024
#define N_OUT    10
#define NOUT_NEU 128
#define SIMBLK   256          // 4-split x 64 batches
#define PROJBLK  1600         // 100 t x 16 ctiles

typedef unsigned int u32;
typedef unsigned long long u64;
typedef unsigned short u16;
typedef double f64x4 __attribute__((ext_vector_type(4)));

// ---------------- prep ----------------
__global__ void k_prep(const float* __restrict__ tau, double* __restrict__ d_syn,
                       double* __restrict__ e_tau, int* __restrict__ inv){
    int n = blockIdx.x * blockDim.x + threadIdx.x;
    if(n < N_NEU){
        double tv = (double)tau[n];
        d_syn[n] = exp(-1.0 / tv);
        e_tau[n] = 2.718281828459045 / tv;   // np.e / tau
        inv[n] = -1;
    }
}

__global__ void k_scatter(const int* __restrict__ idx, int* __restrict__ inv){
    int j = blockIdx.x * blockDim.x + threadIdx.x;
    if(j < NIN_NEU) inv[idx[j]] = j;
}

// zero exch mailboxes + proj row counters (ws poisoned 0xAA; must be 0 each launch)
__global__ void k_zero(u64* __restrict__ exch, int nexch, u32* __restrict__ pcnt, int ncnt){
    int j = blockIdx.x * blockDim.x + threadIdx.x;
    if(j < nexch) exch[j] = 0ull;
    if(j < ncnt)  pcnt[j] = 0u;
}

// ---------------- f64 MFMA layout probe (1 wave) ----------------
__global__ void k_probe(int* __restrict__ flag){
    int l = threadIdx.x & 63;
    double a = (double)((l & 15)*4 + (l >> 4) + 1);
    double b = (double)((l >> 4)*16 + (l & 15) + 1);
    f64x4 acc = {0.0, 0.0, 0.0, 0.0};
    acc = __builtin_amdgcn_mfma_f64_16x16x4f64(a, b, acc, 0, 0, 0);
    bool oka = true, okb = true;
    int j = l & 15;
    #pragma unroll
    for(int r=0;r<4;r++){
        int ia = 4*(l >> 4) + r;
        int ib = (l >> 4) + 4*r;
        double expA = 0.0, expB = 0.0;
        #pragma unroll
        for(int k=0;k<4;k++){
            expA += (double)((4*ia + k + 1) * (16*k + j + 1));
            expB += (double)((4*ib + k + 1) * (16*k + j + 1));
        }
        oka = oka && (acc[r] == expA);
        okb = okb && (acc[r] == expB);
    }
    bool alla = __all(oka), allb = __all(okb);
    if(threadIdx.x == 0) *flag = alla ? 0 : (allb ? 1 : 2);
}

// ---------------- W transpose: Wt[m][n] = Wrec[n][m] ----------------
__global__ __launch_bounds__(256) void k_tr(const float* __restrict__ Wrec, float* __restrict__ Wt){
    __shared__ float tile[32][33];
    int bx = blockIdx.x, by = blockIdx.y;
    int txx = threadIdx.x, tyy = threadIdx.y;          // (32, 8)
    #pragma unroll
    for(int j=0;j<4;j++)
        tile[tyy+8*j][txx] = Wrec[(size_t)(by*32 + tyy+8*j)*N_NEU + bx*32 + txx];
    __syncthreads();
    #pragma unroll
    for(int j=0;j<4;j++)
        Wt[(size_t)(bx*32 + tyy+8*j)*N_NEU + by*32 + txx] = tile[txx][tyy+8*j];
}

// ================= mega kernel: PROJ blocks [0,1600) + SIM blocks [1600,1856) =================
// PROJ first in dispatch order: proj blocks never wait, so sim blocks (which spin on proj
// rows) can only be dispatched after all proj blocks — worst case degrades to serial
// proj-then-sim, never a deadlock. __launch_bounds__(512,4) caps VGPR at 128 so 2 blocks/CU
// co-reside and sim overlaps the proj tail.
// proj publishes projC via atomicExch (coherent L3) then bumps projCnt[t] (16 tiles/row).
// sim (round-10-verified internals) reads proj via atomicAdd(.,0.0), polls projCnt[t+1]
// inside the existing sibling-poll window.
__global__ __launch_bounds__(512, 4) void k_mega(
        const float* __restrict__ X, const float* __restrict__ Win,
        const int* __restrict__ flagp,
        double* __restrict__ projC, const float* __restrict__ Wt,
        const double* __restrict__ dsyn, const double* __restrict__ etau,
        const int* __restrict__ inv,
        u64* __restrict__ exch, u32* __restrict__ projCnt,
        double* __restrict__ cntout){
    __shared__ __align__(16) char smem[20992];

    if(blockIdx.x >= PROJBLK){
        // ---------------- SIM role ----------------
        double (*Ip)[512] = (double(*)[512])smem;             // 16384 B
        u32* words = (u32*)(smem + 16384);                    // 256 B
        u16* list  = (u16*)(smem + 16640);                    // 4096 B
        int* cntSp = (int*)(smem + 20736);

        const int bid = blockIdx.x - PROJBLK;
        const int b   = bid >> 2;
        const int q   = bid & 3;
        const int tid = threadIdx.x;
        const int n   = q*512 + tid;
        const int team = tid >> 7;
        const int c4   = (tid & 127) * 4;
        const float*  WtQ   = Wt + q*512;
        const double* projB = projC + (size_t)b*TT*NIN_NEU;

        u64* myE = exch + (size_t)bid*32;

        const double ds = dsyn[n], et = etau[n];
        const int jv = inv[n];
        const double dasc = exp(-0.0125);
        double v=-60.0, psc=0.0, rise=0.0, asc=0.0, ref=0.0, spk=0.0, creg=0.0;

        if(tid == 0){
            *cntSp = 0;
            while(atomicAdd(&projCnt[0], 0u) < 16u) __builtin_amdgcn_s_sleep(2);  // row 0 ready
        }
        __syncthreads();

        for(int t=0;t<TT;t++){
            // external drive: coherent RMW read (row t readiness confirmed last step)
            double pp = 0.0;
            if(jv >= 0) pp = atomicAdd((double*)(projB + (size_t)t*NIN_NEU + jv), 0.0);

            // ---- gather over my quarter of the ordered spike list, cols [c4,c4+4) ----
            const int cc  = *cntSp;
            const int beg = (cc * team)     >> 2;
            const int end = (cc * (team+1)) >> 2;
            double I[4] = {0.0, 0.0, 0.0, 0.0};
            int i = beg;
            for(; i + 8 <= end; i += 8){
                int m[8];
                #pragma unroll
                for(int u=0;u<8;u++) m[u] = list[i+u];
                float4 wv[8];
                #pragma unroll
                for(int u=0;u<8;u++)
                    wv[u] = *reinterpret_cast<const float4*>(WtQ + ((size_t)m[u] << 11) + c4);
                #pragma unroll
                for(int u=0;u<8;u++){
                    I[0] += (double)wv[u].x; I[1] += (double)wv[u].y;
                    I[2] += (double)wv[u].z; I[3] += (double)wv[u].w;
                }
            }
            for(; i < end; ++i){
                int mm = list[i];
                float4 w4 = *reinterpret_cast<const float4*>(WtQ + ((size_t)mm << 11) + c4);
                I[0] += (double)w4.x; I[1] += (double)w4.y;
                I[2] += (double)w4.z; I[3] += (double)w4.w;
            }
            #pragma unroll
            for(int u=0;u<4;u++) Ip[team][c4+u] = I[u];
            __syncthreads();

            // ---- combine partials (fixed order) + external drive ----
            double Irec = Ip[0][tid] + Ip[1][tid] + Ip[2][tid] + Ip[3][tid] + pp;

            // ---- neuron update (verified arithmetic, unchanged) ----
            double psc_n  = ds * (psc + rise);
            double rise_n = ds * rise + et * Irec;
            double asc_n  = dasc * asc + (-0.2) * spk;
            double act    = (ref <= 0.0) ? 1.0 : 0.0;
            double dv  = (psc_n + asc_n + 0.12) / 2.0 - (v - (-60.0)) / 20.0;
            double v_n = v + act * dv;
            double s_n = ((v_n - (-45.0)) >= 0.0) ? act : 0.0;
            v_n = v_n - s_n * 15.0;
            double ref_n = (s_n > 0.0) ? 2.0 : fmax(ref - 1.0, 0.0);
            v = v_n; psc = psc_n; rise = rise_n; asc = asc_n; ref = ref_n; spk = s_n;
            creg += s_n;

            // ---- publish own ballots: LDS words + tagged mailbox (atomicExch RMW) ----
            u64 bal = __ballot(s_n > 0.0);
            int w = tid >> 6, lane = tid & 63;
            u64 tagv = ((u64)(t+1)) << 32;
            if(lane == 0){
                u32 lo = (u32)bal, hi = (u32)(bal >> 32);
                words[q*16 + 2*w]     = lo;
                words[q*16 + 2*w + 1] = hi;
                u64* dst = myE + (size_t)(t & 1)*16;
                atomicExch(&dst[2*w],     tagv | (u64)lo);
                atomicExch(&dst[2*w + 1], tagv | (u64)hi);
            }
            // ---- poll 3 siblings (tid<48) + next proj row (tid==48) ----
            if(tid < 48){
                int pidx = tid >> 4;
                int w2   = tid & 15;
                int q2   = pidx + (pidx >= q ? 1 : 0);
                u64* src = exch + (size_t)(b*4 + q2)*32 + (size_t)(t & 1)*16;
                u64 val = atomicAdd(&src[w2], 0ull);
                while((val >> 32) != (u64)(t+1)){
                    __builtin_amdgcn_s_sleep(1);
                    val = atomicAdd(&src[w2], 0ull);
                }
                words[q2*16 + w2] = (u32)val;
            } else if(tid == 48 && t+1 < TT){
                while(atomicAdd(&projCnt[t+1], 0u) < 16u) __builtin_amdgcn_s_sleep(1);
            }
            __syncthreads();

            // ---- wave 0: ordered compaction of full-network words into list ----
            if(tid < 64){
                u32 wv = words[tid];
                int c = __popc(wv);
                int incl = c;
                #pragma unroll
                for(int off=1; off<64; off<<=1){
                    int x = __shfl_up(incl, off);
                    if(tid >= off) incl += x;
                }
                int excl = incl - c;
                u32 z = wv;
                int base = tid * 32;
                while(z){
                    int bp = __ffs(z) - 1;
                    z &= z - 1;
                    list[excl++] = (u16)(base + bp);
                }
                if(tid == 63) *cntSp = incl;
            }
            __syncthreads();
        }

        cntout[(size_t)b*N_NEU + n] = creg;
        return;
    }

    // ---------------- PROJ role (blocks 0..1599; never waits on anything) ----------------
    float (*As)[81] = (float(*)[81])smem;              // 10368 B
    float (*Bs)[81] = (float(*)[81])(smem + 10368);    // 10368 B
    const int bi  = blockIdx.x;                        // 0..1599
    const int t   = bi >> 4;
    const int c0  = (bi & 15) * 64;
    const int tid = threadIdx.x;
    const int flag = *flagp;
    const int lr = tid >> 3;            // 0..63 staging row
    const int lk = (tid & 7) * 4;       // staging k base

    if(flag < 2){
        const int w   = tid >> 6;       // 0..7
        const int l   = tid & 63;
        const int g   = l >> 4;
        const int cl  = l & 15;
        const int r0w = (w & 3) * 16;
        const int cb  = (w >> 2) * 2;   // ctile pair base

        f64x4 acc[2] = {{0.,0.,0.,0.},{0.,0.,0.,0.}};
        for(int k0 = 0; k0 < KIN; k0 += 32){
            int kk = k0 + lk;
            float a4[4] = {0.f,0.f,0.f,0.f}, b4[4] = {0.f,0.f,0.f,0.f};
            if(kk + 4 <= KIN){
                float4 ra = *reinterpret_cast<const float4*>(X   + (size_t)(t*64 + lr)*KIN + kk);
                float4 rb = *reinterpret_cast<const float4*>(Win + (size_t)(c0 + lr)*KIN + kk);
                a4[0]=ra.x; a4[1]=ra.y; a4[2]=ra.z; a4[3]=ra.w;
                b4[0]=rb.x; b4[1]=rb.y; b4[2]=rb.z; b4[3]=rb.w;
            }
            #pragma unroll
            for(int e=0;e<4;e++){ As[lk+e][lr] = a4[e]; Bs[lk+e][lr] = b4[e]; }
            __syncthreads();
            #pragma unroll
            for(int kq=0;kq<8;kq++){
                double a  = (double)As[kq*4 + g][r0w + cl];
                double b0 = (double)Bs[kq*4 + g][(cb+0)*16 + cl];
                double b1 = (double)Bs[kq*4 + g][(cb+1)*16 + cl];
                acc[0] = __builtin_amdgcn_mfma_f64_16x16x4f64(a, b0, acc[0], 0, 0, 0);
                acc[1] = __builtin_amdgcn_mfma_f64_16x16x4f64(a, b1, acc[1], 0, 0, 0);
            }
            __syncthreads();
        }
        #pragma unroll
        for(int ccq=0;ccq<2;ccq++){
            int c = c0 + (cb+ccq)*16 + cl;
            #pragma unroll
            for(int j=0;j<4;j++){
                int br = r0w + ((flag == 0) ? (4*g + j) : (g + 4*j));
                atomicExch((u64*)&projC[((size_t)br*TT + t)*NIN_NEU + c],
                           __double_as_longlong(acc[ccq][j]));
            }
        }
    } else {
        // VALU fallback (runs only if MFMA layout probe failed)
        const int r2 = (tid >> 4) * 2;
        const int cf = (tid & 15) * 4;
        double acc[2][4] = {};
        for(int k0 = 0; k0 < KIN; k0 += 32){
            int kk = k0 + lk;
            float a4[4] = {0.f,0.f,0.f,0.f}, b4[4] = {0.f,0.f,0.f,0.f};
            if(kk + 4 <= KIN){
                float4 ra = *reinterpret_cast<const float4*>(X   + (size_t)(t*64 + lr)*KIN + kk);
                float4 rb = *reinterpret_cast<const float4*>(Win + (size_t)(c0 + lr)*KIN + kk);
                a4[0]=ra.x; a4[1]=ra.y; a4[2]=ra.z; a4[3]=ra.w;
                b4[0]=rb.x; b4[1]=rb.y; b4[2]=rb.z; b4[3]=rb.w;
            }
            #pragma unroll
            for(int e=0;e<4;e++){ As[lk+e][lr] = a4[e]; Bs[lk+e][lr] = b4[e]; }
            __syncthreads();
            #pragma unroll
            for(int kkk=0;kkk<32;kkk++){
                double a0 = (double)As[kkk][r2], a1 = (double)As[kkk][r2+1];
                #pragma unroll
                for(int j=0;j<4;j++){
                    double bb = (double)Bs[kkk][cf+j];
                    acc[0][j] += a0*bb;
                    acc[1][j] += a1*bb;
                }
            }
            __syncthreads();
        }
        #pragma unroll
        for(int i2=0;i2<2;i2++)
            #pragma unroll
            for(int j=0;j<4;j++)
                atomicExch((u64*)&projC[((size_t)(r2+i2)*TT + t)*NIN_NEU + c0 + cf + j],
                           __double_as_longlong(acc[i2][j]));
    }
    __syncthreads();                    // drains vmcnt: tile atomics acked at L3
    if(tid == 0) atomicAdd(&projCnt[t], 1u);
}

// ---------------- readout ----------------
__global__ void k_final(const double* __restrict__ cnt, const int* __restrict__ oidx,
                        const float* __restrict__ Wout, float* __restrict__ out){
    int i = blockIdx.x * blockDim.x + threadIdx.x;
    if(i >= BB * N_OUT) return;
    int b = i / N_OUT, o = i - b * N_OUT;
    double accv = 0.0;
    for(int j=0;j<NOUT_NEU;j++){
        double rate = cnt[(size_t)b*N_NEU + oidx[j]] / 100.0;
        accv += rate * (double)Wout[o*NOUT_NEU + j];
    }
    out[i] = (float)accv;
}

extern "C" void kernel_launch(void* const* d_in, const int* in_sizes, int n_in,
                              void* d_out, int out_size, void* d_ws, size_t ws_size,
                              hipStream_t stream){
    const float* X    = (const float*)d_in[0];
    const float* Win  = (const float*)d_in[1];
    const float* Wrec = (const float*)d_in[2];
    const float* Wout = (const float*)d_in[3];
    const float* tau  = (const float*)d_in[4];
    const int*   iidx = (const int*)d_in[5];
    const int*   oidx = (const int*)d_in[6];
    float* out = (float*)d_out;

    char* w = (char*)d_ws;
    const size_t OFF_PROJ = 0;                                      // 52,428,800
    const size_t OFF_CNT  = OFF_PROJ + (size_t)BB*TT*NIN_NEU*8;     // 1,048,576
    const size_t OFF_WT   = OFF_CNT + (size_t)BB*N_NEU*8;           // 16,777,216
    const size_t OFF_EXCH = OFF_WT + (size_t)N_NEU*N_NEU*4;         // 65,536
    const size_t OFF_PCNT = OFF_EXCH + 65536;                       // 512
    const size_t OFF_DS   = OFF_PCNT + 512;
    const size_t OFF_ET   = OFF_DS + N_NEU*8;
    const size_t OFF_INV  = OFF_ET + N_NEU*8;
    const size_t OFF_FLAG = OFF_INV + N_NEU*4;

    double* projC = (double*)(w + OFF_PROJ);
    double* cnt   = (double*)(w + OFF_CNT);
    float*  Wt    = (float*)(w + OFF_WT);
    u64*    exch  = (u64*)(w + OFF_EXCH);
    u32*    pcnt  = (u32*)(w + OFF_PCNT);
    double* dsyn  = (double*)(w + OFF_DS);
    double* etau  = (double*)(w + OFF_ET);
    int*    inv   = (int*)(w + OFF_INV);
    int*    flag  = (int*)(w + OFF_FLAG);

    k_prep   <<<dim3(8),      dim3(256),  0, stream>>>(tau, dsyn, etau, inv);
    k_scatter<<<dim3(4),      dim3(256),  0, stream>>>(iidx, inv);
    k_zero   <<<dim3(32),     dim3(256),  0, stream>>>(exch, 8192, pcnt, 128);
    k_probe  <<<dim3(1),      dim3(64),   0, stream>>>(flag);
    k_tr     <<<dim3(64,64),  dim3(32,8), 0, stream>>>(Wrec, Wt);
    k_mega   <<<dim3(PROJBLK + SIMBLK), dim3(512), 0, stream>>>(
                 X, Win, flag, projC, Wt, dsyn, etau, inv, exch, pcnt, cnt);
    k_final  <<<dim3(3),      dim3(256),  0, stream>>>(cnt, oidx, Wout, out);
}

// Round 15
// 595.256 us; speedup vs baseline: 1.2497x; 1.2497x over previous
//
#include <hip/hip_runtime.h>
#include <math.h>

#define N_NEU    2048
#define BB       64
#define TT       100
#define KIN      784
#define NIN_NEU  1024
#define N_OUT    10
#define NOUT_NEU 128
#define PROJBLK  1600     // 100 t x 16 ctiles
#define TRBLK    1024     // 32x32 tiles of 64x64

typedef unsigned int u32;
typedef unsigned long long u64;
typedef unsigned short u16;
typedef double f64x4 __attribute__((ext_vector_type(4)));

// ---------------- fused setup: block0 = neuron consts + inv/scatter,
//                  block1 = zero exch mailboxes, block2 = f64 MFMA layout probe ----------------
__global__ void k_setup(const float* __restrict__ tau, const int* __restrict__ iidx,
                        double* __restrict__ d_syn, double* __restrict__ e_tau,
                        int* __restrict__ inv, u64* __restrict__ exch, int* __restrict__ flag){
    const int tid = threadIdx.x;
    if(blockIdx.x == 0){
        for(int n = tid; n < N_NEU; n += 256){
            double tv = (double)tau[n];
            d_syn[n] = exp(-1.0 / tv);
            e_tau[n] = 2.718281828459045 / tv;   // np.e / tau
            inv[n] = -1;
        }
        __syncthreads();
        for(int j = tid; j < NIN_NEU; j += 256) inv[iidx[j]] = j;
    } else if(blockIdx.x == 1){
        for(int i = tid; i < 8192; i += 256) exch[i] = 0ull;   // tags MUST be 0 each launch
    } else {
        if(tid < 64){
            int l = tid;
            double a = (double)((l & 15)*4 + (l >> 4) + 1);
            double b = (double)((l >> 4)*16 + (l & 15) + 1);
            f64x4 acc = {0.0, 0.0, 0.0, 0.0};
            acc = __builtin_amdgcn_mfma_f64_16x16x4f64(a, b, acc, 0, 0, 0);
            bool oka = true, okb = true;
            int j = l & 15;
            #pragma unroll
            for(int r=0;r<4;r++){
                int ia = 4*(l >> 4) + r;
                int ib = (l >> 4) + 4*r;
                double expA = 0.0, expB = 0.0;
                #pragma unroll
                for(int k=0;k<4;k++){
                    expA += (double)((4*ia + k + 1) * (16*k + j + 1));
                    expB += (double)((4*ib + k + 1) * (16*k + j + 1));
                }
                oka = oka && (acc[r] == expA);
                okb = okb && (acc[r] == expB);
            }
            bool alla = __all(oka), allb = __all(okb);
            if(tid == 0) *flag = alla ? 0 : (allb ? 1 : 2);
        }
    }
}

// ================= fused proj + transpose: blocks [0,1600) proj, [1600,2624) tr =================
// No role waits on anything -> no scheduling hazard. Plain stores; k_sim (next launch) reads
// across the kernel boundary (coherent). Proj arithmetic byte-identical to the verified round-10
// k_proj_mfma / k_proj_valu; tr byte-identical to the verified k_tr.
__global__ __launch_bounds__(256) void k_projtr(
        const float* __restrict__ X, const float* __restrict__ Win,
        const float* __restrict__ Wrec, const int* __restrict__ flagp,
        double* __restrict__ projC, float* __restrict__ Wt){
    __shared__ __align__(16) char smem[20736];
    const int tid = threadIdx.x;

    if(blockIdx.x >= PROJBLK){
        // ---------------- TRANSPOSE role: Wt[m][n] = Wrec[n][m], 64x64 tiles ----------------
        float (*tile)[65] = (float(*)[65])smem;           // 16640 B
        const int ti = blockIdx.x - PROJBLK;              // 0..1023
        const int tx = ti & 31, ty = ti >> 5;             // tile coords
        const int c  = tid & 63;
        const int r0 = tid >> 6;                          // 0..3
        #pragma unroll
        for(int k=0;k<16;k++){
            int r = r0 + 4*k;
            tile[r][c] = Wrec[(size_t)(ty*64 + r)*N_NEU + tx*64 + c];
        }
        __syncthreads();
        #pragma unroll
        for(int k=0;k<16;k++){
            int rr = r0 + 4*k;
            Wt[(size_t)(tx*64 + rr)*N_NEU + ty*64 + c] = tile[c][rr];
        }
        return;
    }

    // ---------------- PROJ role: projC[b][t][c] = sum_k X[t*64+b][k] * Win[c][k] ----------------
    const int bi  = blockIdx.x;
    const int t   = bi >> 4;
    const int c0  = (bi & 15) * 64;
    const int flag = *flagp;
    const int lr  = tid >> 2;            // staging row 0..63
    const int lk  = (tid & 3) * 8;       // staging k base

    if(flag < 2){
        float (*As)[81] = (float(*)[81])smem;             // 10368 B
        float (*Bs)[81] = (float(*)[81])(smem + 10368);   // 10368 B
        const int w   = tid >> 6;
        const int l   = tid & 63;
        const int g   = l >> 4;
        const int cl  = l & 15;

        f64x4 acc[4] = {{0.,0.,0.,0.},{0.,0.,0.,0.},{0.,0.,0.,0.},{0.,0.,0.,0.}};
        for(int k0 = 0; k0 < KIN; k0 += 32){
            int kk = k0 + lk;
            float a8[8], b8[8];
            if(kk + 8 <= KIN){
                const float* pa = X   + (size_t)(t*64 + lr)*KIN + kk;
                const float* pb = Win + (size_t)(c0 + lr)*KIN + kk;
                float4 ra0 = *reinterpret_cast<const float4*>(pa);
                float4 ra1 = *reinterpret_cast<const float4*>(pa + 4);
                float4 rb0 = *reinterpret_cast<const float4*>(pb);
                float4 rb1 = *reinterpret_cast<const float4*>(pb + 4);
                a8[0]=ra0.x; a8[1]=ra0.y; a8[2]=ra0.z; a8[3]=ra0.w;
                a8[4]=ra1.x; a8[5]=ra1.y; a8[6]=ra1.z; a8[7]=ra1.w;
                b8[0]=rb0.x; b8[1]=rb0.y; b8[2]=rb0.z; b8[3]=rb0.w;
                b8[4]=rb1.x; b8[5]=rb1.y; b8[6]=rb1.z; b8[7]=rb1.w;
            } else {
                #pragma unroll
                for(int e=0;e<8;e++){ a8[e]=0.0f; b8[e]=0.0f; }
            }
            #pragma unroll
            for(int e=0;e<8;e++){ As[lk+e][lr] = a8[e]; Bs[lk+e][lr] = b8[e]; }
            __syncthreads();
            #pragma unroll
            for(int kq=0;kq<8;kq++){
                double a = (double)As[kq*4 + g][w*16 + cl];
                #pragma unroll
                for(int ct=0;ct<4;ct++){
                    double bb = (double)Bs[kq*4 + g][ct*16 + cl];
                    acc[ct] = __builtin_amdgcn_mfma_f64_16x16x4f64(a, bb, acc[ct], 0, 0, 0);
                }
            }
            __syncthreads();
        }
        #pragma unroll
        for(int ct=0;ct<4;ct++){
            int c = c0 + ct*16 + cl;
            #pragma unroll
            for(int j=0;j<4;j++){
                int b = w*16 + ((flag == 0) ? (4*g + j) : (g + 4*j));
                projC[((size_t)b*TT + t)*NIN_NEU + c] = acc[ct][j];
            }
        }
    } else {
        // VALU fallback (runs only if MFMA layout probe failed)
        float (*As)[68] = (float(*)[68])smem;             // 8704 B
        float (*Bs)[68] = (float(*)[68])(smem + 8704);    // 8704 B
        const int txq = tid & 15, tyq = tid >> 4;
        double acc[4][4] = {};
        for(int k0 = 0; k0 < KIN; k0 += 32){
            int kk = k0 + lk;
            float a8[8], b8[8];
            if(kk + 8 <= KIN){
                const float* pa = X   + (size_t)(t*64 + lr)*KIN + kk;
                const float* pb = Win + (size_t)(c0 + lr)*KIN + kk;
                float4 ra0 = *reinterpret_cast<const float4*>(pa);
                float4 ra1 = *reinterpret_cast<const float4*>(pa + 4);
                float4 rb0 = *reinterpret_cast<const float4*>(pb);
                float4 rb1 = *reinterpret_cast<const float4*>(pb + 4);
                a8[0]=ra0.x; a8[1]=ra0.y; a8[2]=ra0.z; a8[3]=ra0.w;
                a8[4]=ra1.x; a8[5]=ra1.y; a8[6]=ra1.z; a8[7]=ra1.w;
                b8[0]=rb0.x; b8[1]=rb0.y; b8[2]=rb0.z; b8[3]=rb0.w;
                b8[4]=rb1.x; b8[5]=rb1.y; b8[6]=rb1.z; b8[7]=rb1.w;
            } else {
                #pragma unroll
                for(int e=0;e<8;e++){ a8[e]=0.0f; b8[e]=0.0f; }
            }
            #pragma unroll
            for(int e=0;e<8;e++){ As[lk+e][lr] = a8[e]; Bs[lk+e][lr] = b8[e]; }
            __syncthreads();
            #pragma unroll
            for(int kkk=0;kkk<32;kkk++){
                float4 af = *reinterpret_cast<const float4*>(&As[kkk][tyq*4]);
                float4 bf = *reinterpret_cast<const float4*>(&Bs[kkk][txq*4]);
                double a[4] = {(double)af.x,(double)af.y,(double)af.z,(double)af.w};
                double b[4] = {(double)bf.x,(double)bf.y,(double)bf.z,(double)bf.w};
                #pragma unroll
                for(int i=0;i<4;i++)
                    #pragma unroll
                    for(int j=0;j<4;j++)
                        acc[i][j] += a[i]*b[j];
            }
            __syncthreads();
        }
        #pragma unroll
        for(int j=0;j<4;j++){
            int c = c0 + txq*4 + j;
            #pragma unroll
            for(int i=0;i<4;i++){
                int b = tyq*4 + i;
                projC[((size_t)b*TT + t)*NIN_NEU + c] = acc[i][j];
            }
        }
    }
}

// ---------------- per-(batch,quarter) simulation: 256 blocks x 512 threads ----------------
// Round-10-verified. Block bid = b*4 + q owns batch b, neurons [q*512, q*512+512).
// Spike quarters exchanged via tag+payload u64 packets using RMW atomics only.
__global__ __launch_bounds__(512) void k_sim(
        const double* __restrict__ projC, const float* __restrict__ Wt,
        const double* __restrict__ dsyn, const double* __restrict__ etau,
        const int* __restrict__ inv,
        u64* __restrict__ exch, double* __restrict__ cntout){
    __shared__ double Ip[4][512];
    __shared__ u32 words[64];
    __shared__ u16 list[N_NEU];
    __shared__ int cntS;

    const int bid = blockIdx.x;
    const int b   = bid >> 2;
    const int q   = bid & 3;
    const int tid = threadIdx.x;
    const int n   = q*512 + tid;
    const int team = tid >> 7;
    const int c4   = (tid & 127) * 4;
    const float*  WtQ   = Wt + q*512;
    const double* projB = projC + (size_t)b*TT*NIN_NEU;

    u64* myE = exch + (size_t)bid*32;

    const double ds = dsyn[n], et = etau[n];
    const int jv = inv[n];
    const double dasc = exp(-0.0125);
    double v=-60.0, psc=0.0, rise=0.0, asc=0.0, ref=0.0, spk=0.0, creg=0.0;

    if(tid == 0) cntS = 0;
    __syncthreads();

    for(int t=0;t<TT;t++){
        double pp = (jv >= 0) ? projB[(size_t)t*NIN_NEU + jv] : 0.0;

        const int cc  = cntS;
        const int beg = (cc * team)     >> 2;
        const int end = (cc * (team+1)) >> 2;
        double I[4] = {0.0, 0.0, 0.0, 0.0};
        int i = beg;
        for(; i + 8 <= end; i += 8){
            int m[8];
            #pragma unroll
            for(int u=0;u<8;u++) m[u] = list[i+u];
            float4 wv[8];
            #pragma unroll
            for(int u=0;u<8;u++)
                wv[u] = *reinterpret_cast<const float4*>(WtQ + ((size_t)m[u] << 11) + c4);
            #pragma unroll
            for(int u=0;u<8;u++){
                I[0] += (double)wv[u].x; I[1] += (double)wv[u].y;
                I[2] += (double)wv[u].z; I[3] += (double)wv[u].w;
            }
        }
        for(; i < end; ++i){
            int mm = list[i];
            float4 w4 = *reinterpret_cast<const float4*>(WtQ + ((size_t)mm << 11) + c4);
            I[0] += (double)w4.x; I[1] += (double)w4.y;
            I[2] += (double)w4.z; I[3] += (double)w4.w;
        }
        #pragma unroll
        for(int u=0;u<4;u++) Ip[team][c4+u] = I[u];
        __syncthreads();

        double Irec = Ip[0][tid] + Ip[1][tid] + Ip[2][tid] + Ip[3][tid] + pp;

        double psc_n  = ds * (psc + rise);
        double rise_n = ds * rise + et * Irec;
        double asc_n  = dasc * asc + (-0.2) * spk;
        double act    = (ref <= 0.0) ? 1.0 : 0.0;
        double dv  = (psc_n + asc_n + 0.12) / 2.0 - (v - (-60.0)) / 20.0;
        double v_n = v + act * dv;
        double s_n = ((v_n - (-45.0)) >= 0.0) ? act : 0.0;
        v_n = v_n - s_n * 15.0;
        double ref_n = (s_n > 0.0) ? 2.0 : fmax(ref - 1.0, 0.0);
        v = v_n; psc = psc_n; rise = rise_n; asc = asc_n; ref = ref_n; spk = s_n;
        creg += s_n;

        u64 bal = __ballot(s_n > 0.0);
        int w = tid >> 6, lane = tid & 63;
        u64 tagv = ((u64)(t+1)) << 32;
        if(lane == 0){
            u32 lo = (u32)bal, hi = (u32)(bal >> 32);
            words[q*16 + 2*w]     = lo;
            words[q*16 + 2*w + 1] = hi;
            u64* dst = myE + (size_t)(t & 1)*16;
            atomicExch(&dst[2*w],     tagv | (u64)lo);
            atomicExch(&dst[2*w + 1], tagv | (u64)hi);
        }
        if(tid < 48){
            int pidx = tid >> 4;
            int w2   = tid & 15;
            int q2   = pidx + (pidx >= q ? 1 : 0);
            u64* src = exch + (size_t)(b*4 + q2)*32 + (size_t)(t & 1)*16;
            u64 val = atomicAdd(&src[w2], 0ull);
            while((val >> 32) != (u64)(t+1)){
                __builtin_amdgcn_s_sleep(1);
                val = atomicAdd(&src[w2], 0ull);
            }
            words[q2*16 + w2] = (u32)val;
        }
        __syncthreads();

        if(tid < 64){
            u32 wv = words[tid];
            int c = __popc(wv);
            int incl = c;
            #pragma unroll
            for(int off=1; off<64; off<<=1){
                int x = __shfl_up(incl, off);
                if(tid >= off) incl += x;
            }
            int excl = incl - c;
            u32 z = wv;
            int base = tid * 32;
            while(z){
                int bp = __ffs(z) - 1;
                z &= z - 1;
                list[excl++] = (u16)(base + bp);
            }
            if(tid == 63) cntS = incl;
        }
        __syncthreads();
    }

    cntout[(size_t)b*N_NEU + n] = creg;
}

// ---------------- readout ----------------
__global__ void k_final(const double* __restrict__ cnt, const int* __restrict__ oidx,
                        const float* __restrict__ Wout, float* __restrict__ out){
    int i = blockIdx.x * blockDim.x + threadIdx.x;
    if(i >= BB * N_OUT) return;
    int b = i / N_OUT, o = i - b * N_OUT;
    double accv = 0.0;
    for(int j=0;j<NOUT_NEU;j++){
        double rate = cnt[(size_t)b*N_NEU + oidx[j]] / 100.0;
        accv += rate * (double)Wout[o*NOUT_NEU + j];
    }
    out[i] = (float)accv;
}

extern "C" void kernel_launch(void* const* d_in, const int* in_sizes, int n_in,
                              void* d_out, int out_size, void* d_ws, size_t ws_size,
                              hipStream_t stream){
    const float* X    = (const float*)d_in[0];
    const float* Win  = (const float*)d_in[1];
    const float* Wrec = (const float*)d_in[2];
    const float* Wout = (const float*)d_in[3];
    const float* tau  = (const float*)d_in[4];
    const int*   iidx = (const int*)d_in[5];
    const int*   oidx = (const int*)d_in[6];
    float* out = (float*)d_out;

    char* w = (char*)d_ws;
    const size_t OFF_PROJ = 0;                                      // 52,428,800
    const size_t OFF_CNT  = OFF_PROJ + (size_t)BB*TT*NIN_NEU*8;     // 1,048,576
    const size_t OFF_WT   = OFF_CNT + (size_t)BB*N_NEU*8;           // 16,777,216
    const size_t OFF_EXCH = OFF_WT + (size_t)N_NEU*N_NEU*4;         // 65,536
    const size_t OFF_DS   = OFF_EXCH + 65536;
    const size_t OFF_ET   = OFF_DS + N_NEU*8;
    const size_t OFF_INV  = OFF_ET + N_NEU*8;
    const size_t OFF_FLAG = OFF_INV + N_NEU*4;

    double* projC = (double*)(w + OFF_PROJ);
    double* cnt   = (double*)(w + OFF_CNT);
    float*  Wt    = (float*)(w + OFF_WT);
    u64*    exch  = (u64*)(w + OFF_EXCH);
    double* dsyn  = (double*)(w + OFF_DS);
    double* etau  = (double*)(w + OFF_ET);
    int*    inv   = (int*)(w + OFF_INV);
    int*    flag  = (int*)(w + OFF_FLAG);

    k_setup <<<dim3(3),               dim3(256), 0, stream>>>(tau, iidx, dsyn, etau, inv, exch, flag);
    k_projtr<<<dim3(PROJBLK + TRBLK), dim3(256), 0, stream>>>(X, Win, Wrec, flag, projC, Wt);
    k_sim   <<<dim3(4*BB),            dim3(512), 0, stream>>>(projC, Wt, dsyn, etau, inv, exch, cnt);
    k_final <<<dim3(3),               dim3(256), 0, stream>>>(cnt, oidx, Wout, out);
}

// Round 16
// 574.190 us; speedup vs baseline: 1.2956x; 1.0367x over previous
//
#include <hip/hip_runtime.h>
#include <math.h>

#define N_NEU    2048
#define BB       64
#define TT       100
#define KIN      784
#define NIN_NEU  1024
#define N_OUT    10
#define NOUT_NEU 128

typedef unsigned int u32;
typedef unsigned long long u64;
typedef unsigned short u16;
typedef double f64x4 __attribute__((ext_vector_type(4)));

// ---------------- fused setup: block0 = neuron consts + inv/scatter,
//                  block1 = zero exch mailboxes, block2 = f64 MFMA layout probe ----------------
__global__ void k_setup(const float* __restrict__ tau, const int* __restrict__ iidx,
                        double* __restrict__ d_syn, double* __restrict__ e_tau,
                        int* __restrict__ inv, u64* __restrict__ exch, int* __restrict__ flag){
    const int tid = threadIdx.x;
    if(blockIdx.x == 0){
        for(int n = tid; n < N_NEU; n += 256){
            double tv = (double)tau[n];
            d_syn[n] = exp(-1.0 / tv);
            e_tau[n] = 2.718281828459045 / tv;   // np.e / tau
            inv[n] = -1;
        }
        __syncthreads();
        for(int j = tid; j < NIN_NEU; j += 256) inv[iidx[j]] = j;
    } else if(blockIdx.x == 1){
        for(int i = tid; i < 8192; i += 256) exch[i] = 0ull;   // tags MUST be 0 each launch
    } else {
        if(tid < 64){
            int l = tid;
            double a = (double)((l & 15)*4 + (l >> 4) + 1);
            double b = (double)((l >> 4)*16 + (l & 15) + 1);
            f64x4 acc = {0.0, 0.0, 0.0, 0.0};
            acc = __builtin_amdgcn_mfma_f64_16x16x4f64(a, b, acc, 0, 0, 0);
            bool oka = true, okb = true;
            int j = l & 15;
            #pragma unroll
            for(int r=0;r<4;r++){
                int ia = 4*(l >> 4) + r;
                int ib = (l >> 4) + 4*r;
                double expA = 0.0, expB = 0.0;
                #pragma unroll
                for(int k=0;k<4;k++){
                    expA += (double)((4*ia + k + 1) * (16*k + j + 1));
                    expB += (double)((4*ib + k + 1) * (16*k + j + 1));
                }
                oka = oka && (acc[r] == expA);
                okb = okb && (acc[r] == expB);
            }
            bool alla = __all(oka), allb = __all(okb);
            if(tid == 0) *flag = alla ? 0 : (allb ? 1 : 2);
        }
    }
}

// ---------------- W transpose: Wt[m][n] = Wrec[n][m] (round-10 verbatim) ----------------
__global__ __launch_bounds__(256) void k_tr(const float* __restrict__ Wrec, float* __restrict__ Wt){
    __shared__ float tile[32][33];
    int bx = blockIdx.x, by = blockIdx.y;
    int txx = threadIdx.x, tyy = threadIdx.y;          // (32, 8)
    #pragma unroll
    for(int j=0;j<4;j++)
        tile[tyy+8*j][txx] = Wrec[(size_t)(by*32 + tyy+8*j)*N_NEU + bx*32 + txx];
    __syncthreads();
    #pragma unroll
    for(int j=0;j<4;j++)
        Wt[(size_t)(bx*32 + tyy+8*j)*N_NEU + by*32 + txx] = tile[txx][tyy+8*j];
}

// ---------------- input projection GEMM via f64 MFMA (runs iff flag<2; round-10 verbatim) ----------------
// projC[b][t][c] = sum_k X[t*64+b][k] * Win[c][k]
__global__ __launch_bounds__(256) void k_proj_mfma(const float* __restrict__ X, const float* __restrict__ Win,
                                                   const int* __restrict__ flagp, double* __restrict__ projC){
    const int flag = *flagp;
    if(flag >= 2) return;
    __shared__ float As[32][81];   // As[k][row]
    __shared__ float Bs[32][81];   // Bs[k][col]
    const int t   = blockIdx.x;
    const int c0  = blockIdx.y * 64;
    const int tid = threadIdx.x;
    const int w   = tid >> 6;
    const int l   = tid & 63;
    const int g   = l >> 4;
    const int cl  = l & 15;
    const int lr  = tid >> 2;
    const int lk  = (tid & 3) * 8;

    f64x4 acc[4] = {{0.,0.,0.,0.},{0.,0.,0.,0.},{0.,0.,0.,0.},{0.,0.,0.,0.}};

    for(int k0 = 0; k0 < KIN; k0 += 32){
        int kk = k0 + lk;
        float a8[8], b8[8];
        if(kk + 8 <= KIN){
            const float* pa = X   + (size_t)(t*64 + lr)*KIN + kk;
            const float* pb = Win + (size_t)(c0 + lr)*KIN + kk;
            float4 ra0 = *reinterpret_cast<const float4*>(pa);
            float4 ra1 = *reinterpret_cast<const float4*>(pa + 4);
            float4 rb0 = *reinterpret_cast<const float4*>(pb);
            float4 rb1 = *reinterpret_cast<const float4*>(pb + 4);
            a8[0]=ra0.x; a8[1]=ra0.y; a8[2]=ra0.z; a8[3]=ra0.w;
            a8[4]=ra1.x; a8[5]=ra1.y; a8[6]=ra1.z; a8[7]=ra1.w;
            b8[0]=rb0.x; b8[1]=rb0.y; b8[2]=rb0.z; b8[3]=rb0.w;
            b8[4]=rb1.x; b8[5]=rb1.y; b8[6]=rb1.z; b8[7]=rb1.w;
        } else {
            #pragma unroll
            for(int e=0;e<8;e++){ a8[e]=0.0f; b8[e]=0.0f; }
        }
        #pragma unroll
        for(int e=0;e<8;e++){ As[lk+e][lr] = a8[e]; Bs[lk+e][lr] = b8[e]; }
        __syncthreads();

        #pragma unroll
        for(int kq=0;kq<8;kq++){
            double a = (double)As[kq*4 + g][w*16 + cl];
            #pragma unroll
            for(int ct=0;ct<4;ct++){
                double bb = (double)Bs[kq*4 + g][ct*16 + cl];
                acc[ct] = __builtin_amdgcn_mfma_f64_16x16x4f64(a, bb, acc[ct], 0, 0, 0);
            }
        }
        __syncthreads();
    }

    #pragma unroll
    for(int ct=0;ct<4;ct++){
        int c = c0 + ct*16 + cl;
        #pragma unroll
        for(int j=0;j<4;j++){
            int b = w*16 + ((flag == 0) ? (4*g + j) : (g + 4*j));
            projC[((size_t)b*TT + t)*NIN_NEU + c] = acc[ct][j];
        }
    }
}

// ---------------- VALU fallback projection (runs iff flag==2; round-10 verbatim) ----------------
__global__ __launch_bounds__(256) void k_proj_valu(const float* __restrict__ X, const float* __restrict__ Win,
                                                   const int* __restrict__ flagp, double* __restrict__ projC){
    if(*flagp < 2) return;
    __shared__ float As[32][68];
    __shared__ float Bs[32][68];
    const int r0 = blockIdx.x * 64;
    const int c0 = blockIdx.y * 64;
    const int t  = threadIdx.x;
    const int lr = t >> 2;
    const int lk = (t & 3) * 8;
    const int tx = t & 15, ty = t >> 4;
    double acc[4][4] = {};
    for(int k0 = 0; k0 < KIN; k0 += 32){
        int kk = k0 + lk;
        float a8[8], b8[8];
        if(kk + 8 <= KIN){
            const float* pa = X   + (size_t)(r0+lr)*KIN + kk;
            const float* pb = Win + (size_t)(c0+lr)*KIN + kk;
            float4 ra0 = *reinterpret_cast<const float4*>(pa);
            float4 ra1 = *reinterpret_cast<const float4*>(pa + 4);
            float4 rb0 = *reinterpret_cast<const float4*>(pb);
            float4 rb1 = *reinterpret_cast<const float4*>(pb + 4);
            a8[0]=ra0.x; a8[1]=ra0.y; a8[2]=ra0.z; a8[3]=ra0.w;
            a8[4]=ra1.x; a8[5]=ra1.y; a8[6]=ra1.z; a8[7]=ra1.w;
            b8[0]=rb0.x; b8[1]=rb0.y; b8[2]=rb0.z; b8[3]=rb0.w;
            b8[4]=rb1.x; b8[5]=rb1.y; b8[6]=rb1.z; b8[7]=rb1.w;
        } else {
            #pragma unroll
            for(int e=0;e<8;e++){ a8[e]=0.0f; b8[e]=0.0f; }
        }
        #pragma unroll
        for(int e=0;e<8;e++){ As[lk+e][lr] = a8[e]; Bs[lk+e][lr] = b8[e]; }
        __syncthreads();
        #pragma unroll
        for(int kkk=0;kkk<32;kkk++){
            float4 af = *reinterpret_cast<const float4*>(&As[kkk][ty*4]);
            float4 bf = *reinterpret_cast<const float4*>(&Bs[kkk][tx*4]);
            double a[4] = {(double)af.x,(double)af.y,(double)af.z,(double)af.w};
            double b[4] = {(double)bf.x,(double)bf.y,(double)bf.z,(double)bf.w};
            #pragma unroll
            for(int i=0;i<4;i++)
                #pragma unroll
                for(int j=0;j<4;j++)
                    acc[i][j] += a[i]*b[j];
        }
        __syncthreads();
    }
    const int tt = blockIdx.x;
    #pragma unroll
    for(int j=0;j<4;j++){
        int c = c0 + tx*4 + j;
        #pragma unroll
        for(int i=0;i<4;i++){
            int b = ty*4 + i;
            projC[((size_t)b*TT + tt)*NIN_NEU + c] = acc[i][j];
        }
    }
}

// ---------------- per-(batch,quarter) simulation: 256 blocks x 512 threads (round-10 verbatim) ----------------
__global__ __launch_bounds__(512) void k_sim(
        const double* __restrict__ projC, const float* __restrict__ Wt,
        const double* __restrict__ dsyn, const double* __restrict__ etau,
        const int* __restrict__ inv,
        u64* __restrict__ exch, double* __restrict__ cntout){
    __shared__ double Ip[4][512];
    __shared__ u32 words[64];
    __shared__ u16 list[N_NEU];
    __shared__ int cntS;

    const int bid = blockIdx.x;
    const int b   = bid >> 2;
    const int q   = bid & 3;
    const int tid = threadIdx.x;
    const int n   = q*512 + tid;
    const int team = tid >> 7;
    const int c4   = (tid & 127) * 4;
    const float*  WtQ   = Wt + q*512;
    const double* projB = projC + (size_t)b*TT*NIN_NEU;

    u64* myE = exch + (size_t)bid*32;

    const double ds = dsyn[n], et = etau[n];
    const int jv = inv[n];
    const double dasc = exp(-0.0125);
    double v=-60.0, psc=0.0, rise=0.0, asc=0.0, ref=0.0, spk=0.0, creg=0.0;

    if(tid == 0) cntS = 0;
    __syncthreads();

    for(int t=0;t<TT;t++){
        double pp = (jv >= 0) ? projB[(size_t)t*NIN_NEU + jv] : 0.0;

        const int cc  = cntS;
        const int beg = (cc * team)     >> 2;
        const int end = (cc * (team+1)) >> 2;
        double I[4] = {0.0, 0.0, 0.0, 0.0};
        int i = beg;
        for(; i + 8 <= end; i += 8){
            int m[8];
            #pragma unroll
            for(int u=0;u<8;u++) m[u] = list[i+u];
            float4 wv[8];
            #pragma unroll
            for(int u=0;u<8;u++)
                wv[u] = *reinterpret_cast<const float4*>(WtQ + ((size_t)m[u] << 11) + c4);
            #pragma unroll
            for(int u=0;u<8;u++){
                I[0] += (double)wv[u].x; I[1] += (double)wv[u].y;
                I[2] += (double)wv[u].z; I[3] += (double)wv[u].w;
            }
        }
        for(; i < end; ++i){
            int mm = list[i];
            float4 w4 = *reinterpret_cast<const float4*>(WtQ + ((size_t)mm << 11) + c4);
            I[0] += (double)w4.x; I[1] += (double)w4.y;
            I[2] += (double)w4.z; I[3] += (double)w4.w;
        }
        #pragma unroll
        for(int u=0;u<4;u++) Ip[team][c4+u] = I[u];
        __syncthreads();

        double Irec = Ip[0][tid] + Ip[1][tid] + Ip[2][tid] + Ip[3][tid] + pp;

        double psc_n  = ds * (psc + rise);
        double rise_n = ds * rise + et * Irec;
        double asc_n  = dasc * asc + (-0.2) * spk;
        double act    = (ref <= 0.0) ? 1.0 : 0.0;
        double dv  = (psc_n + asc_n + 0.12) / 2.0 - (v - (-60.0)) / 20.0;
        double v_n = v + act * dv;
        double s_n = ((v_n - (-45.0)) >= 0.0) ? act : 0.0;
        v_n = v_n - s_n * 15.0;
        double ref_n = (s_n > 0.0) ? 2.0 : fmax(ref - 1.0, 0.0);
        v = v_n; psc = psc_n; rise = rise_n; asc = asc_n; ref = ref_n; spk = s_n;
        creg += s_n;

        u64 bal = __ballot(s_n > 0.0);
        int w = tid >> 6, lane = tid & 63;
        u64 tagv = ((u64)(t+1)) << 32;
        if(lane == 0){
            u32 lo = (u32)bal, hi = (u32)(bal >> 32);
            words[q*16 + 2*w]     = lo;
            words[q*16 + 2*w + 1] = hi;
            u64* dst = myE + (size_t)(t & 1)*16;
            atomicExch(&dst[2*w],     tagv | (u64)lo);
            atomicExch(&dst[2*w + 1], tagv | (u64)hi);
        }
        if(tid < 48){
            int pidx = tid >> 4;
            int w2   = tid & 15;
            int q2   = pidx + (pidx >= q ? 1 : 0);
            u64* src = exch + (size_t)(b*4 + q2)*32 + (size_t)(t & 1)*16;
            u64 val = atomicAdd(&src[w2], 0ull);
            while((val >> 32) != (u64)(t+1)){
                __builtin_amdgcn_s_sleep(1);
                val = atomicAdd(&src[w2], 0ull);
            }
            words[q2*16 + w2] = (u32)val;
        }
        __syncthreads();

        if(tid < 64){
            u32 wv = words[tid];
            int c = __popc(wv);
            int incl = c;
            #pragma unroll
            for(int off=1; off<64; off<<=1){
                int x = __shfl_up(incl, off);
                if(tid >= off) incl += x;
            }
            int excl = incl - c;
            u32 z = wv;
            int base = tid * 32;
            while(z){
                int bp = __ffs(z) - 1;
                z &= z - 1;
                list[excl++] = (u16)(base + bp);
            }
            if(tid == 63) cntS = incl;
        }
        __syncthreads();
    }

    cntout[(size_t)b*N_NEU + n] = creg;
}

// ---------------- readout ----------------
__global__ void k_final(const double* __restrict__ cnt, const int* __restrict__ oidx,
                        const float* __restrict__ Wout, float* __restrict__ out){
    int i = blockIdx.x * blockDim.x + threadIdx.x;
    if(i >= BB * N_OUT) return;
    int b = i / N_OUT, o = i - b * N_OUT;
    double accv = 0.0;
    for(int j=0;j<NOUT_NEU;j++){
        double rate = cnt[(size_t)b*N_NEU + oidx[j]] / 100.0;
        accv += rate * (double)Wout[o*NOUT_NEU + j];
    }
    out[i] = (float)accv;
}

extern "C" void kernel_launch(void* const* d_in, const int* in_sizes, int n_in,
                              void* d_out, int out_size, void* d_ws, size_t ws_size,
                              hipStream_t stream){
    const float* X    = (const float*)d_in[0];
    const float* Win  = (const float*)d_in[1];
    const float* Wrec = (const float*)d_in[2];
    const float* Wout = (const float*)d_in[3];
    const float* tau  = (const float*)d_in[4];
    const int*   iidx = (const int*)d_in[5];
    const int*   oidx = (const int*)d_in[6];
    float* out = (float*)d_out;

    char* w = (char*)d_ws;
    const size_t OFF_PROJ = 0;                                      // 52,428,800
    const size_t OFF_CNT  = OFF_PROJ + (size_t)BB*TT*NIN_NEU*8;     // 1,048,576
    const size_t OFF_WT   = OFF_CNT + (size_t)BB*N_NEU*8;           // 16,777,216
    const size_t OFF_EXCH = OFF_WT + (size_t)N_NEU*N_NEU*4;         // 65,536
    const size_t OFF_DS   = OFF_EXCH + 65536;
    const size_t OFF_ET   = OFF_DS + N_NEU*8;
    const size_t OFF_INV  = OFF_ET + N_NEU*8;
    const size_t OFF_FLAG = OFF_INV + N_NEU*4;

    double* projC = (double*)(w + OFF_PROJ);
    double* cnt   = (double*)(w + OFF_CNT);
    float*  Wt    = (float*)(w + OFF_WT);
    u64*    exch  = (u64*)(w + OFF_EXCH);
    double* dsyn  = (double*)(w + OFF_DS);
    double* etau  = (double*)(w + OFF_ET);
    int*    inv   = (int*)(w + OFF_INV);
    int*    flag  = (int*)(w + OFF_FLAG);

    k_setup    <<<dim3(3),      dim3(256),  0, stream>>>(tau, iidx, dsyn, etau, inv, exch, flag);
    k_tr       <<<dim3(64,64),  dim3(32,8), 0, stream>>>(Wrec, Wt);
    k_proj_mfma<<<dim3(100,16), dim3(256),  0, stream>>>(X, Win, flag, projC);
    k_proj_valu<<<dim3(100,16), dim3(256),  0, stream>>>(X, Win, flag, projC);
    k_sim      <<<dim3(4*BB),   dim3(512),  0, stream>>>(projC, Wt, dsyn, etau, inv, exch, cnt);
    k_final    <<<dim3(3),      dim3(256),  0, stream>>>(cnt, oidx, Wout, out);
}